// Round 3
// baseline (390.982 us; speedup 1.0000x reference)
//
#include <hip/hip_runtime.h>

#define NH 4
#define HD 32
#define ST 64          // tokens per window (8x8)
#define CD 128         // DIM
#define IMG 102400     // U*V*H*W
#define VHW 20480      // V*H*W
#define HW_ 4096       // H*W
#define SCALE_ 0.17677669529663687f   // 32^-0.5

typedef __attribute__((ext_vector_type(8))) short bf16x8;
typedef __attribute__((ext_vector_type(4))) float f32x4;
typedef __attribute__((ext_vector_type(4))) int   i32x4;
typedef __attribute__((ext_vector_type(2))) int   i32x2;

__device__ __forceinline__ short f2bf(float f) {
    unsigned int u = __float_as_uint(f);
    u = (u + 0x7FFF + ((u >> 16) & 1)) >> 16;   // RNE
    return (short)u;
}

// packed 2xf32 -> 2xbf16 in one VALU instruction
__device__ __forceinline__ int cvt_pk_bf16(float lo, float hi) {
    int r;
    asm("v_cvt_pk_bf16_f32 %0, %1, %2" : "=v"(r) : "v"(lo), "v"(hi));
    return r;
}

// DPP rotate within each row of 16 lanes: pure-VALU cross-lane (no DS pipe)
template <int N>
__device__ __forceinline__ float row_ror(float v) {
    return __int_as_float(__builtin_amdgcn_update_dpp(
        0, __float_as_int(v), 0x120 | N, 0xF, 0xF, true));
}

// ---- fp32 -> bf16 weight conversion + dense bias table into workspace
// bias layout: bt[h][qi][ln][nt]  (4*64*16*4 floats) so the kernel reads float4
__global__ void cvt_w_kernel(const float* __restrict__ qkv_w,
                             const float* __restrict__ proj_w,
                             const float* __restrict__ rpb,
                             short* __restrict__ wq,
                             short* __restrict__ wp,
                             float* __restrict__ bt) {
    int i = blockIdx.x * 256 + threadIdx.x;   // 81920 threads
    if (i < 49152) wq[i] = f2bf(qkv_w[i]);
    else if (i < 65536) wp[i - 49152] = f2bf(proj_w[i - 49152]);
    else if (i < 81920) {
        int j = i - 65536;                    // bt[h][qi][ln][nt]
        int hh = j >> 12, qi = (j >> 6) & 63, ln2 = (j >> 2) & 15, nt = j & 3;
        int kcol = nt * 16 + ln2;
        int ridx = ((qi >> 3) - (kcol >> 3) + 7) * 15 + ((qi & 7) - (kcol & 7) + 7);
        bt[j] = rpb[ridx * 4 + hh];
    }
}

__device__ __forceinline__ long win_addr(int wid, int gr, int ghalf) {
    const int wn = wid & 7, hn = (wid >> 3) & 7;
    int rem = wid >> 6;
    const int v = rem % 5; rem /= 5;
    const int u = rem % 5;
    const int b = rem / 5;
    const int hh_r = (((hn << 3) + gr) - 4) & 63;
    const int ww0  = (((wn << 3) + ghalf * 4) - 4) & 63;
    return (long)b * (CD * IMG) + u * VHW + v * HW_ + hh_r * 64 + ww0;
}

// LDS map (shorts; total 38400 = 75 KB -> 2 blocks/CU):
//  X [0, 8704)                      64 x 136  (X ONLY; never aliased — enables
//                                   cross-window pipelining of next X)
//  head h chunk at 8704 + h*5120:   Q_h [64][40], K_h [64][40]; P_h aliases (64x72)
//  V at 29184 + h*2304:             per head 32 x 72 (d-major)
//  O  [8704, 17408)                 64 x 136 (aliases Q/K heads 0-1; after B3)
//  F  fp32 at short-offset 8704:    128 x 68 floats (aliases O + Q/K; after B5)
//
// Barriers per window (5): B_A (X+prev-F reads done, before QKV scatter),
//  B3 (P reads done, before O write), B4 (O ready), B5 (proj reads done,
//  before F write), B6 (next X ready).  F write->read is same-wave
//  (reader wave = cb>>2 = writer wave), needs no barrier.

template <bool DB>   // DB: dense bias table available in ws
__global__ __launch_bounds__(256, 2)
void win_attn_mfma(const float* __restrict__ x,
                   const short* __restrict__ wq,     // bf16 [384][128]
                   const float* __restrict__ qkv_b,
                   const short* __restrict__ wp,     // bf16 [128][128]
                   const float* __restrict__ proj_b,
                   const float* __restrict__ bias,   // DB ? bt[4][64][16][4] : rpb
                   float* __restrict__ out) {
    __shared__ __align__(16) short smem[38400];

    const int t    = threadIdx.x;
    const int h    = __builtin_amdgcn_readfirstlane(t >> 6);  // wave = head
    const int ln   = t & 15;
    const int quad = (t >> 4) & 3;

    // gather/scatter mapping
    const int s     = t & 15;
    const int cb    = t >> 4;          // 0..15, channels cb*8 .. cb*8+7
    const int gr    = s >> 1;          // window row 0..7
    const int ghalf = s & 1;           // px group 0..1 (4 px each)
    const int srow4 = s * 4;           // gr*8 + ghalf*4

    // persistent grid: 512 blocks, 64 per XCD; XCD x owns windows x*400..x*400+399
    const int xcd  = blockIdx.x & 7;
    const int slot = blockIdx.x >> 3;              // 0..63
    const int nwin = (slot < 16) ? 7 : 6;          // 16*7 + 48*6 = 400
    const int wbase = xcd * 400 + slot;

    short* X  = smem;                      // [64][136]
    short* Qh = smem + 8704 + h * 5120;    // [64][40]
    short* Kh = Qh + 2560;                 // [64][40]
    short* Ph = Qh;                        // aliases Q_h/K_h (in-wave only), [64][72]
    short* Vh = smem + 29184 + h * 2304;   // [32][72]
    short* O  = smem + 8704;               // [64][136]
    float* F  = (float*)(smem + 8704);     // [128][68]

    // ---- persistent per-block state: weights + biases (loaded once) ----
    bf16x8 wqf[24];
    #pragma unroll
    for (int kh = 0; kh < 4; ++kh)
        #pragma unroll
        for (int n = 0; n < 6; ++n)
            wqf[kh * 6 + n] = *(const bf16x8*)(wq + (h * 96 + n * 16 + ln) * 128 + kh * 32 + quad * 8);
    float qb[6];
    #pragma unroll
    for (int n = 0; n < 6; ++n) qb[n] = qkv_b[h * 96 + n * 16 + ln];
    float pb[2];
    #pragma unroll
    for (int nt = 0; nt < 2; ++nt) pb[nt] = proj_b[h * 32 + nt * 16 + ln];
    const float* bt = DB ? (bias + h * 4096) : bias;

    // ---- prologue: gather + pack window 0 into X ----
    long cur_pix = win_addr(wbase, gr, ghalf);
    {
        float4 xv0[8];
        #pragma unroll
        for (int j = 0; j < 8; ++j)
            xv0[j] = *(const float4*)(x + cur_pix + (long)(cb * 8 + j) * IMG);
        #pragma unroll
        for (int px = 0; px < 4; ++px) {
            i32x4 pk;
            #pragma unroll
            for (int j2 = 0; j2 < 4; ++j2)
                pk[j2] = cvt_pk_bf16(((const float*)&xv0[2 * j2])[px],
                                     ((const float*)&xv0[2 * j2 + 1])[px]);
            *(i32x4*)(X + (srow4 + px) * 136 + cb * 8) = pk;
        }
    }
    __syncthreads();                       // X(0) ready

    for (int k = 0; k < nwin; ++k) {
        // ================= QKV GEMM: (64x128) @ (128x384)^T =================
        f32x4 acc[6][4];
        #pragma unroll
        for (int n = 0; n < 6; ++n)
            #pragma unroll
            for (int mt = 0; mt < 4; ++mt) acc[n][mt] = (f32x4){0.f, 0.f, 0.f, 0.f};

        #pragma unroll
        for (int kh = 0; kh < 4; ++kh) {
            bf16x8 af[4];
            #pragma unroll
            for (int mt = 0; mt < 4; ++mt)
                af[mt] = *(const bf16x8*)(X + (mt * 16 + ln) * 136 + kh * 32 + quad * 8);
            #pragma unroll
            for (int n = 0; n < 6; ++n)
                #pragma unroll
                for (int mt = 0; mt < 4; ++mt)
                    acc[n][mt] = __builtin_amdgcn_mfma_f32_16x16x32_bf16(af[mt], wqf[kh * 6 + n], acc[n][mt], 0, 0, 0);
        }
        __syncthreads();   // B_A: X reads + prev-window F reads done

        // ---- issue next window's gather now; hides under attention+proj ----
        const bool has_nxt = (k + 1 < nwin);
        long nxt_pix = 0;
        float4 xv[8];
        if (has_nxt) {
            nxt_pix = win_addr(wbase + (k + 1) * 64, gr, ghalf);
            #pragma unroll
            for (int j = 0; j < 8; ++j)
                xv[j] = *(const float4*)(x + nxt_pix + (long)(cb * 8 + j) * IMG);
        }

        // ---- D-tiles -> LDS: Q (scaled) / K token-major (scalar) ----
        #pragma unroll
        for (int n = 0; n < 4; ++n) {
            const float bv_ = qb[n];
            short* dst = (n < 2) ? Qh : Kh;
            const int col = (n & 1) * 16 + ln;
            #pragma unroll
            for (int mt = 0; mt < 4; ++mt)
                #pragma unroll
                for (int r = 0; r < 4; ++r) {
                    const float val = acc[n][mt][r] + bv_;
                    const int tk = mt * 16 + quad * 4 + r;
                    dst[tk * 40 + col] = f2bf((n < 2) ? val * SCALE_ : val);
                }
        }
        // ---- V d-major: 4 consecutive tokens -> packed b64 stores ----
        #pragma unroll
        for (int n = 4; n < 6; ++n) {
            const float bv_ = qb[n];
            const int d = (n - 4) * 16 + ln;
            #pragma unroll
            for (int mt = 0; mt < 4; ++mt) {
                const int tk0 = mt * 16 + quad * 4;
                i32x2 pv;
                pv[0] = cvt_pk_bf16(acc[n][mt][0] + bv_, acc[n][mt][1] + bv_);
                pv[1] = cvt_pk_bf16(acc[n][mt][2] + bv_, acc[n][mt][3] + bv_);
                *(i32x2*)(Vh + d * 72 + tk0) = pv;
            }
        }
        // Q/K/V/P strictly per-head, per-wave: no barrier until O write.

        // ================= S = Q K^T (64x64, K=32) =================
        bf16x8 aq[4], bk[4];
        #pragma unroll
        for (int mt = 0; mt < 4; ++mt) aq[mt] = *(const bf16x8*)(Qh + (mt * 16 + ln) * 40 + quad * 8);
        #pragma unroll
        for (int nt = 0; nt < 4; ++nt) bk[nt] = *(const bf16x8*)(Kh + (nt * 16 + ln) * 40 + quad * 8);
        f32x4 sm[4][4];
        #pragma unroll
        for (int mt = 0; mt < 4; ++mt)
            #pragma unroll
            for (int nt = 0; nt < 4; ++nt) {
                f32x4 z = (f32x4){0.f, 0.f, 0.f, 0.f};
                sm[mt][nt] = __builtin_amdgcn_mfma_f32_16x16x32_bf16(aq[mt], bk[nt], z, 0, 0, 0);
            }

        // relative-position bias
        if (DB) {
            #pragma unroll
            for (int mt = 0; mt < 4; ++mt)
                #pragma unroll
                for (int r = 0; r < 4; ++r) {
                    const int qi = mt * 16 + quad * 4 + r;
                    const f32x4 b4 = *(const f32x4*)(bt + (qi * 16 + ln) * 4);
                    #pragma unroll
                    for (int nt = 0; nt < 4; ++nt)
                        sm[mt][nt][r] += b4[nt];
                }
        } else {
            #pragma unroll
            for (int nt = 0; nt < 4; ++nt) {
                const int kcol = nt * 16 + ln;
                const int ik = kcol >> 3, jk = kcol & 7;
                #pragma unroll
                for (int mt = 0; mt < 4; ++mt)
                    #pragma unroll
                    for (int r = 0; r < 4; ++r) {
                        const int q = mt * 16 + quad * 4 + r;
                        const int ridx = ((q >> 3) - ik + 7) * 15 + ((q & 7) - jk + 7);
                        sm[mt][nt][r] += bt[ridx * 4 + h];
                    }
            }
        }

        // softmax rows: row=(mt,r); cols span nt x 16 lanes of the quad (DPP reduce)
        float inv[4][4];
        #pragma unroll
        for (int mt = 0; mt < 4; ++mt)
            #pragma unroll
            for (int r = 0; r < 4; ++r) {
                float m = fmaxf(fmaxf(sm[mt][0][r], sm[mt][1][r]), fmaxf(sm[mt][2][r], sm[mt][3][r]));
                m = fmaxf(m, row_ror<1>(m));
                m = fmaxf(m, row_ror<2>(m));
                m = fmaxf(m, row_ror<4>(m));
                m = fmaxf(m, row_ror<8>(m));
                float sum = 0.f;
                #pragma unroll
                for (int nt = 0; nt < 4; ++nt) {
                    float e = __expf(sm[mt][nt][r] - m);
                    sm[mt][nt][r] = e;
                    sum += e;
                }
                sum += row_ror<1>(sum);
                sum += row_ror<2>(sum);
                sum += row_ror<4>(sum);
                sum += row_ror<8>(sum);
                inv[mt][r] = 1.f / sum;
                const int q = mt * 16 + quad * 4 + r;
                #pragma unroll
                for (int nt = 0; nt < 4; ++nt)
                    Ph[q * 72 + nt * 16 + ln] = f2bf(sm[mt][nt][r]);   // unnormalized P
            }

        // proj B-fragments (L2-hot; hidden under PV)
        bf16x8 wpf[8];
        #pragma unroll
        for (int kt = 0; kt < 4; ++kt)
            #pragma unroll
            for (int nt = 0; nt < 2; ++nt)
                wpf[kt * 2 + nt] = *(const bf16x8*)(wp + (h * 32 + nt * 16 + ln) * 128 + kt * 32 + quad * 8);

        // ================= O = P V (64x32, K=64) =================
        f32x4 oa[4][2];
        #pragma unroll
        for (int mt = 0; mt < 4; ++mt)
            #pragma unroll
            for (int nt = 0; nt < 2; ++nt) oa[mt][nt] = (f32x4){0.f, 0.f, 0.f, 0.f};
        #pragma unroll
        for (int kt = 0; kt < 2; ++kt) {
            bf16x8 ap[4], bv[2];
            #pragma unroll
            for (int mt = 0; mt < 4; ++mt)
                ap[mt] = *(const bf16x8*)(Ph + (mt * 16 + ln) * 72 + kt * 32 + quad * 8);
            #pragma unroll
            for (int nt = 0; nt < 2; ++nt)
                bv[nt] = *(const bf16x8*)(Vh + (nt * 16 + ln) * 72 + kt * 32 + quad * 8);
            #pragma unroll
            for (int mt = 0; mt < 4; ++mt)
                #pragma unroll
                for (int nt = 0; nt < 2; ++nt)
                    oa[mt][nt] = __builtin_amdgcn_mfma_f32_16x16x32_bf16(ap[mt], bv[nt], oa[mt][nt], 0, 0, 0);
        }

        __syncthreads();              // B3: all P reads done before O overwrites Q/K
        #pragma unroll
        for (int mt = 0; mt < 4; ++mt)
            #pragma unroll
            for (int nt = 0; nt < 2; ++nt)
                #pragma unroll
                for (int r = 0; r < 4; ++r)
                    O[(mt * 16 + quad * 4 + r) * 136 + h * 32 + nt * 16 + ln] =
                        f2bf(oa[mt][nt][r] * inv[mt][r]);
        __syncthreads();              // B4: O ready

        // ================= proj: (64x128) @ (128x128)^T =================
        f32x4 pa[4][2];
        #pragma unroll
        for (int mt = 0; mt < 4; ++mt)
            #pragma unroll
            for (int nt = 0; nt < 2; ++nt) pa[mt][nt] = (f32x4){0.f, 0.f, 0.f, 0.f};
        #pragma unroll
        for (int kt = 0; kt < 4; ++kt) {
            bf16x8 ao[4];
            #pragma unroll
            for (int mt = 0; mt < 4; ++mt)
                ao[mt] = *(const bf16x8*)(O + (mt * 16 + ln) * 136 + kt * 32 + quad * 8);
            #pragma unroll
            for (int mt = 0; mt < 4; ++mt)
                #pragma unroll
                for (int nt = 0; nt < 2; ++nt)
                    pa[mt][nt] = __builtin_amdgcn_mfma_f32_16x16x32_bf16(ao[mt], wpf[kt * 2 + nt], pa[mt][nt], 0, 0, 0);
        }

        __syncthreads();              // B5: proj reads done before F overwrites
        // F write: 4 consecutive tokens -> b128 stores (row stride 272B, 16-aligned)
        #pragma unroll
        for (int mt = 0; mt < 4; ++mt)
            #pragma unroll
            for (int nt = 0; nt < 2; ++nt) {
                f32x4 fv = pa[mt][nt] + pb[nt];
                *(f32x4*)(F + (h * 32 + nt * 16 + ln) * 68 + mt * 16 + quad * 4) = fv;
            }

        // F read is same-wave as F write (reader wave = cb>>2 = writer wave):
        // DS in-order per wave -> no barrier needed.
        #pragma unroll
        for (int j = 0; j < 8; ++j) {
            const int c = cb * 8 + j;
            float4 f4 = *(const float4*)(F + c * 68 + srow4);
            *(float4*)(out + cur_pix + (long)c * IMG) = f4;
        }

        // ---- pack next window's X (gather issued pre-attention) ----
        if (has_nxt) {
            #pragma unroll
            for (int px = 0; px < 4; ++px) {
                i32x4 pk;
                #pragma unroll
                for (int j2 = 0; j2 < 4; ++j2)
                    pk[j2] = cvt_pk_bf16(((const float*)&xv[2 * j2])[px],
                                         ((const float*)&xv[2 * j2 + 1])[px]);
                *(i32x4*)(X + (srow4 + px) * 136 + cb * 8) = pk;
            }
            cur_pix = nxt_pix;
            __syncthreads();          // B6: X(k+1) ready
        }
    }
}

// ---------- fp32 fallback (only if workspace is too small even for weights) ----------
__global__ __launch_bounds__(256, 1)
void win_attn_fallback(const float* __restrict__ x,
                       const float* __restrict__ wQKV,
                       const float* __restrict__ qkv_b,
                       const float* __restrict__ wP,
                       const float* __restrict__ proj_b,
                       const float* __restrict__ rpb,
                       float* __restrict__ out) {
    __shared__ __align__(16) float k_lds[NH * ST * HD];
    __shared__ __align__(16) float v_lds[NH * ST * HD];
    const int t = threadIdx.x;
    const int h = __builtin_amdgcn_readfirstlane(t >> 6);
    const int l = t & 63;
    const int wid = blockIdx.x;
    const int wn = wid & 7, hn = (wid >> 3) & 7;
    int rem = wid >> 6;
    const int v = rem % 5; rem /= 5;
    const int u = rem % 5;
    const int b = rem / 5;
    const int hh = (((hn << 3) + (l >> 3)) - 4) & 63;
    const int ww = (((wn << 3) + (l & 7)) - 4) & 63;
    const int pix = b * (NH * HD * IMG) + u * VHW + v * HW_ + hh * 64 + ww;
    float q[HD], kk[HD], vv[HD];
    const float* bq = qkv_b + h * 96;
    #pragma unroll
    for (int d = 0; d < HD; ++d) { q[d] = bq[d]; kk[d] = bq[32 + d]; vv[d] = bq[64 + d]; }
    for (int c = 0; c < CD; ++c) {
        float xv = x[pix + c * IMG];
        const float* wc = wQKV + h * 96 * CD + c;
        #pragma unroll
        for (int d = 0; d < HD; ++d) {
            q[d]  = fmaf(xv, wc[d * CD], q[d]);
            kk[d] = fmaf(xv, wc[(32 + d) * CD], kk[d]);
            vv[d] = fmaf(xv, wc[(64 + d) * CD], vv[d]);
        }
    }
    float* kr = k_lds + (h * ST + l) * HD;
    float* vr = v_lds + (h * ST + l) * HD;
    #pragma unroll
    for (int d = 0; d < HD; ++d) { kr[d] = kk[d]; vr[d] = vv[d]; }
    __syncthreads();
    const float* kh2 = k_lds + h * ST * HD;
    const float* vh2 = v_lds + h * ST * HD;
    const int iq = l >> 3, jq = l & 7;
    float m = -1e30f;
    for (int sk = 0; sk < ST; ++sk) {
        const float* kp = kh2 + sk * HD;
        float a2 = 0.f;
        #pragma unroll
        for (int d = 0; d < HD; ++d) a2 = fmaf(q[d], kp[d], a2);
        int ridx = (iq - (sk >> 3) + 7) * 15 + (jq - (sk & 7) + 7);
        m = fmaxf(m, fmaf(a2, SCALE_, rpb[ridx * 4 + h]));
    }
    float o[HD];
    #pragma unroll
    for (int d = 0; d < HD; ++d) o[d] = 0.f;
    float ssum = 0.f;
    for (int sk = 0; sk < ST; ++sk) {
        const float* kp = kh2 + sk * HD;
        float a2 = 0.f;
        #pragma unroll
        for (int d = 0; d < HD; ++d) a2 = fmaf(q[d], kp[d], a2);
        int ridx = (iq - (sk >> 3) + 7) * 15 + (jq - (sk & 7) + 7);
        float e = __expf(fmaf(a2, SCALE_, rpb[ridx * 4 + h]) - m);
        ssum += e;
        const float* vp = vh2 + sk * HD;
        #pragma unroll
        for (int d = 0; d < HD; ++d) o[d] = fmaf(e, vp[d], o[d]);
    }
    const float inv = 1.f / ssum;
    __syncthreads();
    float* ot = k_lds;
    #pragma unroll
    for (int d = 0; d < HD; ++d) ot[(h * HD + d) * ST + l] = o[d] * inv;
    __syncthreads();
    float o2[HD];
    const float* pb2 = proj_b + h * HD;
    #pragma unroll
    for (int j = 0; j < HD; ++j) o2[j] = pb2[j];
    for (int c = 0; c < CD; ++c) {
        float xv = ot[c * ST + l];
        const float* pc = wP + h * HD * CD + c;
        #pragma unroll
        for (int j = 0; j < HD; ++j) o2[j] = fmaf(xv, pc[j * CD], o2[j]);
    }
    float* ob = out + pix;
    #pragma unroll
    for (int j = 0; j < HD; ++j) ob[(h * HD + j) * IMG] = o2[j];
}

extern "C" void kernel_launch(void* const* d_in, const int* in_sizes, int n_in,
                              void* d_out, int out_size, void* d_ws, size_t ws_size,
                              hipStream_t stream) {
    const float* x      = (const float*)d_in[0];
    const float* qkv_w  = (const float*)d_in[1];
    const float* qkv_b  = (const float*)d_in[2];
    const float* proj_w = (const float*)d_in[3];
    const float* proj_b = (const float*)d_in[4];
    const float* rpb    = (const float*)d_in[5];
    float* out = (float*)d_out;

    const int nW = 2 * 5 * 5 * 8 * 8;  // 3200 windows
    const size_t need_w  = (size_t)(49152 + 16384) * sizeof(short);           // 128 KB
    const size_t need_db = need_w + (size_t)16384 * sizeof(float);            // +64 KB

    if (ws_size >= need_db) {
        short* wqs = (short*)d_ws;
        short* wps = wqs + 49152;
        float* bt  = (float*)(wqs + 65536);
        cvt_w_kernel<<<320, 256, 0, stream>>>(qkv_w, proj_w, rpb, wqs, wps, bt);
        win_attn_mfma<true><<<512, 256, 0, stream>>>(x, wqs, qkv_b, wps, proj_b, bt, out);
    } else if (ws_size >= need_w) {
        short* wqs = (short*)d_ws;
        short* wps = wqs + 49152;
        cvt_w_kernel<<<256, 256, 0, stream>>>(qkv_w, proj_w, rpb, wqs, wps, nullptr);
        win_attn_mfma<false><<<512, 256, 0, stream>>>(x, wqs, qkv_b, wps, proj_b, rpb, out);
    } else {
        win_attn_fallback<<<nW, 256, 0, stream>>>(x, qkv_w, qkv_b, proj_w, proj_b, rpb, out);
    }
}

// Round 4
// 278.897 us; speedup vs baseline: 1.4019x; 1.4019x over previous
//
#include <hip/hip_runtime.h>

#define NH 4
#define HD 32
#define ST 64          // tokens per window (8x8)
#define CD 128         // DIM
#define IMG 102400     // U*V*H*W
#define VHW 20480      // V*H*W
#define HW_ 4096       // H*W
#define SCALE_ 0.17677669529663687f   // 32^-0.5

typedef __attribute__((ext_vector_type(8))) short bf16x8;
typedef __attribute__((ext_vector_type(4))) float f32x4;
typedef __attribute__((ext_vector_type(4))) int   i32x4;
typedef __attribute__((ext_vector_type(2))) int   i32x2;

__device__ __forceinline__ short f2bf(float f) {
    unsigned int u = __float_as_uint(f);
    u = (u + 0x7FFF + ((u >> 16) & 1)) >> 16;   // RNE
    return (short)u;
}

// packed 2xf32 -> 2xbf16 in one VALU instruction
__device__ __forceinline__ int cvt_pk_bf16(float lo, float hi) {
    int r;
    asm("v_cvt_pk_bf16_f32 %0, %1, %2" : "=v"(r) : "v"(lo), "v"(hi));
    return r;
}

// DPP rotate within each row of 16 lanes: pure-VALU cross-lane (no DS pipe)
template <int N>
__device__ __forceinline__ float row_ror(float v) {
    return __int_as_float(__builtin_amdgcn_update_dpp(
        0, __float_as_int(v), 0x120 | N, 0xF, 0xF, true));
}

// ---- fp32 -> bf16 weight conversion + dense bias table into workspace
// bias layout: bt[h][qi][ln][nt]  (4*64*16*4 floats) so the kernel reads float4
__global__ void cvt_w_kernel(const float* __restrict__ qkv_w,
                             const float* __restrict__ proj_w,
                             const float* __restrict__ rpb,
                             short* __restrict__ wq,
                             short* __restrict__ wp,
                             float* __restrict__ bt) {
    int i = blockIdx.x * 256 + threadIdx.x;   // 81920 threads
    if (i < 49152) wq[i] = f2bf(qkv_w[i]);
    else if (i < 65536) wp[i - 49152] = f2bf(proj_w[i - 49152]);
    else if (i < 81920) {
        int j = i - 65536;                    // bt[h][qi][ln][nt]
        int hh = j >> 12, qi = (j >> 6) & 63, ln2 = (j >> 2) & 15, nt = j & 3;
        int kcol = nt * 16 + ln2;
        int ridx = ((qi >> 3) - (kcol >> 3) + 7) * 15 + ((qi & 7) - (kcol & 7) + 7);
        bt[j] = rpb[ridx * 4 + hh];
    }
}

// LDS map (shorts; total 38400 = 75 KB -> 2 blocks/CU):
//  X      [0, 8704)                 64 x 136  (tok-major, 128 ch + pad 8)
//  head h chunk at 8704 + h*5120:  Q_h [64][40], K_h [64][40]; P_h aliases (64x72)
//  V      [29184, 38400)            per head 32 x 72 (d-major)
//  O   aliases [0, 8704)            64 x 136  (after B2; X dead)
//  F fp32 aliases [0, 17408 shorts) 128 x 68 floats (after B4)
//
// Barriers (4): B1 X-ready; B2 pre-O (all waves past X/P/V reads); B3 O-ready;
//  B4 pre-F (all proj reads of O done).  F write->read is same-wave
//  (reader wave = cb>>2 = writer wave), so no F-ready barrier.

template <bool DB>   // DB: dense bias table available in ws
__global__ __launch_bounds__(256, 2)
void win_attn_mfma(const float* __restrict__ x,
                   const short* __restrict__ wq,     // bf16 [384][128]
                   const float* __restrict__ qkv_b,
                   const short* __restrict__ wp,     // bf16 [128][128]
                   const float* __restrict__ proj_b,
                   const float* __restrict__ bias,   // DB ? bt[4][64][16][4] : rpb
                   float* __restrict__ out) {
    __shared__ __align__(16) short smem[38400];

    const int t    = threadIdx.x;
    const int h    = __builtin_amdgcn_readfirstlane(t >> 6);  // wave = head
    const int ln   = t & 15;
    const int quad = (t >> 4) & 3;

    // gather/scatter mapping: s -> (row gr, 4-px group), cb -> channel block
    const int s     = t & 15;
    const int cb    = t >> 4;          // 0..15, channels cb*8 .. cb*8+7
    const int gr    = s >> 1;          // window row 0..7
    const int ghalf = s & 1;           // px group 0..1 (4 px each)
    const int srow4 = s * 4;           // gr*8 + ghalf*4

    // XCD swizzle: give each XCD 400 contiguous logical windows
    const int wid = (blockIdx.x & 7) * 400 + (blockIdx.x >> 3);
    const int wn = wid & 7, hn = (wid >> 3) & 7;
    int rem = wid >> 6;
    const int v = rem % 5; rem /= 5;
    const int u = rem % 5;
    const int b = rem / 5;

    // source pixels: shift by -4 mod 64; 4-px groups stay float4-aligned (4|shift)
    const int hh_r = (((hn << 3) + gr) - 4) & 63;
    const int ww0  = (((wn << 3) + ghalf * 4) - 4) & 63;
    const long pixrs = (long)b * (CD * IMG) + u * VHW + v * HW_ + hh_r * 64 + ww0;

    short* X  = smem;                      // [64][136]
    short* Qh = smem + 8704 + h * 5120;    // [64][40]
    short* Kh = Qh + 2560;                 // [64][40]
    short* Ph = Qh;                        // aliases Q_h/K_h (in-wave only), [64][72]
    short* Vh = smem + 29184 + h * 2304;   // [32][72]
    short* O  = smem;                      // [64][136] (aliases X)
    float* F  = (float*)smem;              // [128][68] (aliases X + QK heads 0-1)

    // ---- float4 gather: 8 vector loads/thread, all in flight ----
    float4 xv[8];
    #pragma unroll
    for (int j = 0; j < 8; ++j)
        xv[j] = *(const float4*)(x + pixrs + (long)(cb * 8 + j) * IMG);

    // ---- prefetch ALL QKV B-fragments (independent of X) ----
    bf16x8 wqf[24];
    #pragma unroll
    for (int kh = 0; kh < 4; ++kh)
        #pragma unroll
        for (int n = 0; n < 6; ++n)
            wqf[kh * 6 + n] = *(const bf16x8*)(wq + (h * 96 + n * 16 + ln) * 128 + kh * 32 + quad * 8);
    float qb[6];
    #pragma unroll
    for (int n = 0; n < 6; ++n) qb[n] = qkv_b[h * 96 + n * 16 + ln];

    // ---- X pack: cvt_pk + b128 stores ----
    #pragma unroll
    for (int px = 0; px < 4; ++px) {
        i32x4 pk;
        #pragma unroll
        for (int j2 = 0; j2 < 4; ++j2)
            pk[j2] = cvt_pk_bf16(((const float*)&xv[2 * j2])[px],
                                 ((const float*)&xv[2 * j2 + 1])[px]);
        *(i32x4*)(X + (srow4 + px) * 136 + cb * 8) = pk;
    }
    __syncthreads();                       // B1: X ready

    // ================= QKV GEMM: (64x128) @ (128x384)^T =================
    f32x4 acc[6][4];
    #pragma unroll
    for (int n = 0; n < 6; ++n)
        #pragma unroll
        for (int mt = 0; mt < 4; ++mt) acc[n][mt] = (f32x4){0.f, 0.f, 0.f, 0.f};

    #pragma unroll
    for (int kh = 0; kh < 4; ++kh) {
        bf16x8 af[4];
        #pragma unroll
        for (int mt = 0; mt < 4; ++mt)
            af[mt] = *(const bf16x8*)(X + (mt * 16 + ln) * 136 + kh * 32 + quad * 8);
        __builtin_amdgcn_s_setprio(1);
        #pragma unroll
        for (int n = 0; n < 6; ++n)
            #pragma unroll
            for (int mt = 0; mt < 4; ++mt)
                acc[n][mt] = __builtin_amdgcn_mfma_f32_16x16x32_bf16(af[mt], wqf[kh * 6 + n], acc[n][mt], 0, 0, 0);
        __builtin_amdgcn_s_setprio(0);
    }

    // ---- D-tiles -> LDS: Q (scaled) / K token-major (scalar) ----
    #pragma unroll
    for (int n = 0; n < 4; ++n) {
        const float bv_ = qb[n];
        short* dst = (n < 2) ? Qh : Kh;
        const int col = (n & 1) * 16 + ln;
        #pragma unroll
        for (int mt = 0; mt < 4; ++mt)
            #pragma unroll
            for (int r = 0; r < 4; ++r) {
                const float val = acc[n][mt][r] + bv_;
                const int tk = mt * 16 + quad * 4 + r;
                dst[tk * 40 + col] = f2bf((n < 2) ? val * SCALE_ : val);
            }
    }
    // ---- V d-major: 4 consecutive tokens -> packed b64 stores ----
    #pragma unroll
    for (int n = 4; n < 6; ++n) {
        const float bv_ = qb[n];
        const int d = (n - 4) * 16 + ln;
        #pragma unroll
        for (int mt = 0; mt < 4; ++mt) {
            const int tk0 = mt * 16 + quad * 4;
            i32x2 pv;
            pv[0] = cvt_pk_bf16(acc[n][mt][0] + bv_, acc[n][mt][1] + bv_);
            pv[1] = cvt_pk_bf16(acc[n][mt][2] + bv_, acc[n][mt][3] + bv_);
            *(i32x2*)(Vh + d * 72 + tk0) = pv;
        }
    }
    // Q/K/V/P strictly per-head, per-wave: no barrier until O overwrites X.

    // ================= S = Q K^T (64x64, K=32) =================
    bf16x8 aq[4], bk[4];
    #pragma unroll
    for (int mt = 0; mt < 4; ++mt) aq[mt] = *(const bf16x8*)(Qh + (mt * 16 + ln) * 40 + quad * 8);
    #pragma unroll
    for (int nt = 0; nt < 4; ++nt) bk[nt] = *(const bf16x8*)(Kh + (nt * 16 + ln) * 40 + quad * 8);
    f32x4 sm[4][4];
    __builtin_amdgcn_s_setprio(1);
    #pragma unroll
    for (int mt = 0; mt < 4; ++mt)
        #pragma unroll
        for (int nt = 0; nt < 4; ++nt) {
            f32x4 z = (f32x4){0.f, 0.f, 0.f, 0.f};
            sm[mt][nt] = __builtin_amdgcn_mfma_f32_16x16x32_bf16(aq[mt], bk[nt], z, 0, 0, 0);
        }
    __builtin_amdgcn_s_setprio(0);

    // relative-position bias
    if (DB) {
        const float* bt = bias + h * 4096;     // [qi][ln][nt], float4 per (qi,ln)
        #pragma unroll
        for (int mt = 0; mt < 4; ++mt)
            #pragma unroll
            for (int r = 0; r < 4; ++r) {
                const int qi = mt * 16 + quad * 4 + r;
                const f32x4 b4 = *(const f32x4*)(bt + (qi * 16 + ln) * 4);
                #pragma unroll
                for (int nt = 0; nt < 4; ++nt)
                    sm[mt][nt][r] += b4[nt];
            }
    } else {
        #pragma unroll
        for (int nt = 0; nt < 4; ++nt) {
            const int kcol = nt * 16 + ln;
            const int ik = kcol >> 3, jk = kcol & 7;
            #pragma unroll
            for (int mt = 0; mt < 4; ++mt)
                #pragma unroll
                for (int r = 0; r < 4; ++r) {
                    const int q = mt * 16 + quad * 4 + r;
                    const int ridx = ((q >> 3) - ik + 7) * 15 + ((q & 7) - jk + 7);
                    sm[mt][nt][r] += bias[ridx * 4 + h];
                }
        }
    }

    // softmax rows: row=(mt,r); cols span nt x 16 lanes of the quad (DPP reduce)
    float inv[4][4];
    #pragma unroll
    for (int mt = 0; mt < 4; ++mt)
        #pragma unroll
        for (int r = 0; r < 4; ++r) {
            float m = fmaxf(fmaxf(sm[mt][0][r], sm[mt][1][r]), fmaxf(sm[mt][2][r], sm[mt][3][r]));
            m = fmaxf(m, row_ror<1>(m));
            m = fmaxf(m, row_ror<2>(m));
            m = fmaxf(m, row_ror<4>(m));
            m = fmaxf(m, row_ror<8>(m));
            float sum = 0.f;
            #pragma unroll
            for (int nt = 0; nt < 4; ++nt) {
                float e = __expf(sm[mt][nt][r] - m);
                sm[mt][nt][r] = e;
                sum += e;
            }
            sum += row_ror<1>(sum);
            sum += row_ror<2>(sum);
            sum += row_ror<4>(sum);
            sum += row_ror<8>(sum);
            inv[mt][r] = 1.f / sum;
            const int q = mt * 16 + quad * 4 + r;
            #pragma unroll
            for (int nt = 0; nt < 4; ++nt)
                Ph[q * 72 + nt * 16 + ln] = f2bf(sm[mt][nt][r]);   // unnormalized P
        }

    // prefetch proj B-fragments during softmax slack
    bf16x8 wpf[8];
    #pragma unroll
    for (int kt = 0; kt < 4; ++kt)
        #pragma unroll
        for (int nt = 0; nt < 2; ++nt)
            wpf[kt * 2 + nt] = *(const bf16x8*)(wp + (h * 32 + nt * 16 + ln) * 128 + kt * 32 + quad * 8);
    float pb[2];
    #pragma unroll
    for (int nt = 0; nt < 2; ++nt) pb[nt] = proj_b[h * 32 + nt * 16 + ln];

    // ================= O = P V (64x32, K=64) =================
    f32x4 oa[4][2];
    #pragma unroll
    for (int mt = 0; mt < 4; ++mt)
        #pragma unroll
        for (int nt = 0; nt < 2; ++nt) oa[mt][nt] = (f32x4){0.f, 0.f, 0.f, 0.f};
    #pragma unroll
    for (int kt = 0; kt < 2; ++kt) {
        bf16x8 ap[4], bv[2];
        #pragma unroll
        for (int mt = 0; mt < 4; ++mt)
            ap[mt] = *(const bf16x8*)(Ph + (mt * 16 + ln) * 72 + kt * 32 + quad * 8);
        #pragma unroll
        for (int nt = 0; nt < 2; ++nt)
            bv[nt] = *(const bf16x8*)(Vh + (nt * 16 + ln) * 72 + kt * 32 + quad * 8);
        __builtin_amdgcn_s_setprio(1);
        #pragma unroll
        for (int mt = 0; mt < 4; ++mt)
            #pragma unroll
            for (int nt = 0; nt < 2; ++nt)
                oa[mt][nt] = __builtin_amdgcn_mfma_f32_16x16x32_bf16(ap[mt], bv[nt], oa[mt][nt], 0, 0, 0);
        __builtin_amdgcn_s_setprio(0);
    }

    __syncthreads();              // B2: all waves past X/P/V reads before O overwrite
    #pragma unroll
    for (int mt = 0; mt < 4; ++mt)
        #pragma unroll
        for (int nt = 0; nt < 2; ++nt)
            #pragma unroll
            for (int r = 0; r < 4; ++r)
                O[(mt * 16 + quad * 4 + r) * 136 + h * 32 + nt * 16 + ln] =
                    f2bf(oa[mt][nt][r] * inv[mt][r]);
    __syncthreads();              // B3: O ready

    // ================= proj: (64x128) @ (128x128)^T =================
    f32x4 pa[4][2];
    #pragma unroll
    for (int mt = 0; mt < 4; ++mt)
        #pragma unroll
        for (int nt = 0; nt < 2; ++nt) pa[mt][nt] = (f32x4){0.f, 0.f, 0.f, 0.f};
    #pragma unroll
    for (int kt = 0; kt < 4; ++kt) {
        bf16x8 ao[4];
        #pragma unroll
        for (int mt = 0; mt < 4; ++mt)
            ao[mt] = *(const bf16x8*)(O + (mt * 16 + ln) * 136 + kt * 32 + quad * 8);
        __builtin_amdgcn_s_setprio(1);
        #pragma unroll
        for (int mt = 0; mt < 4; ++mt)
            #pragma unroll
            for (int nt = 0; nt < 2; ++nt)
                pa[mt][nt] = __builtin_amdgcn_mfma_f32_16x16x32_bf16(ao[mt], wpf[kt * 2 + nt], pa[mt][nt], 0, 0, 0);
        __builtin_amdgcn_s_setprio(0);
    }

    __syncthreads();              // B4: all proj reads of O done before F overwrites
    // F write: 4 consecutive tokens -> b128 stores
    #pragma unroll
    for (int mt = 0; mt < 4; ++mt)
        #pragma unroll
        for (int nt = 0; nt < 2; ++nt) {
            f32x4 fv = pa[mt][nt] + pb[nt];
            *(f32x4*)(F + (h * 32 + nt * 16 + ln) * 68 + mt * 16 + quad * 4) = fv;
        }

    // F read is same-wave as F write (reader wave = cb>>2 = writer wave):
    // per-wave DS ordering + compiler lgkmcnt -> no barrier needed.
    #pragma unroll
    for (int j = 0; j < 8; ++j) {
        const int c = cb * 8 + j;
        float4 f4 = *(const float4*)(F + c * 68 + srow4);
        *(float4*)(out + pixrs + (long)c * IMG) = f4;
    }
}

// ---------- fp32 fallback (only if workspace is too small even for weights) ----------
__global__ __launch_bounds__(256, 1)
void win_attn_fallback(const float* __restrict__ x,
                       const float* __restrict__ wQKV,
                       const float* __restrict__ qkv_b,
                       const float* __restrict__ wP,
                       const float* __restrict__ proj_b,
                       const float* __restrict__ rpb,
                       float* __restrict__ out) {
    __shared__ __align__(16) float k_lds[NH * ST * HD];
    __shared__ __align__(16) float v_lds[NH * ST * HD];
    const int t = threadIdx.x;
    const int h = __builtin_amdgcn_readfirstlane(t >> 6);
    const int l = t & 63;
    const int wid = blockIdx.x;
    const int wn = wid & 7, hn = (wid >> 3) & 7;
    int rem = wid >> 6;
    const int v = rem % 5; rem /= 5;
    const int u = rem % 5;
    const int b = rem / 5;
    const int hh = (((hn << 3) + (l >> 3)) - 4) & 63;
    const int ww = (((wn << 3) + (l & 7)) - 4) & 63;
    const int pix = b * (NH * HD * IMG) + u * VHW + v * HW_ + hh * 64 + ww;
    float q[HD], kk[HD], vv[HD];
    const float* bq = qkv_b + h * 96;
    #pragma unroll
    for (int d = 0; d < HD; ++d) { q[d] = bq[d]; kk[d] = bq[32 + d]; vv[d] = bq[64 + d]; }
    for (int c = 0; c < CD; ++c) {
        float xv = x[pix + c * IMG];
        const float* wc = wQKV + h * 96 * CD + c;
        #pragma unroll
        for (int d = 0; d < HD; ++d) {
            q[d]  = fmaf(xv, wc[d * CD], q[d]);
            kk[d] = fmaf(xv, wc[(32 + d) * CD], kk[d]);
            vv[d] = fmaf(xv, wc[(64 + d) * CD], vv[d]);
        }
    }
    float* kr = k_lds + (h * ST + l) * HD;
    float* vr = v_lds + (h * ST + l) * HD;
    #pragma unroll
    for (int d = 0; d < HD; ++d) { kr[d] = kk[d]; vr[d] = vv[d]; }
    __syncthreads();
    const float* kh2 = k_lds + h * ST * HD;
    const float* vh2 = v_lds + h * ST * HD;
    const int iq = l >> 3, jq = l & 7;
    float m = -1e30f;
    for (int sk = 0; sk < ST; ++sk) {
        const float* kp = kh2 + sk * HD;
        float a2 = 0.f;
        #pragma unroll
        for (int d = 0; d < HD; ++d) a2 = fmaf(q[d], kp[d], a2);
        int ridx = (iq - (sk >> 3) + 7) * 15 + (jq - (sk & 7) + 7);
        m = fmaxf(m, fmaf(a2, SCALE_, rpb[ridx * 4 + h]));
    }
    float o[HD];
    #pragma unroll
    for (int d = 0; d < HD; ++d) o[d] = 0.f;
    float ssum = 0.f;
    for (int sk = 0; sk < ST; ++sk) {
        const float* kp = kh2 + sk * HD;
        float a2 = 0.f;
        #pragma unroll
        for (int d = 0; d < HD; ++d) a2 = fmaf(q[d], kp[d], a2);
        int ridx = (iq - (sk >> 3) + 7) * 15 + (jq - (sk & 7) + 7);
        float e = __expf(fmaf(a2, SCALE_, rpb[ridx * 4 + h]) - m);
        ssum += e;
        const float* vp = vh2 + sk * HD;
        #pragma unroll
        for (int d = 0; d < HD; ++d) o[d] = fmaf(e, vp[d], o[d]);
    }
    const float inv = 1.f / ssum;
    __syncthreads();
    float* ot = k_lds;
    #pragma unroll
    for (int d = 0; d < HD; ++d) ot[(h * HD + d) * ST + l] = o[d] * inv;
    __syncthreads();
    float o2[HD];
    const float* pb2 = proj_b + h * HD;
    #pragma unroll
    for (int j = 0; j < HD; ++j) o2[j] = pb2[j];
    for (int c = 0; c < CD; ++c) {
        float xv = ot[c * ST + l];
        const float* pc = wP + h * HD * CD + c;
        #pragma unroll
        for (int j = 0; j < HD; ++j) o2[j] = fmaf(xv, pc[j * CD], o2[j]);
    }
    float* ob = out + pix;
    #pragma unroll
    for (int j = 0; j < HD; ++j) ob[(h * HD + j) * IMG] = o2[j];
}

extern "C" void kernel_launch(void* const* d_in, const int* in_sizes, int n_in,
                              void* d_out, int out_size, void* d_ws, size_t ws_size,
                              hipStream_t stream) {
    const float* x      = (const float*)d_in[0];
    const float* qkv_w  = (const float*)d_in[1];
    const float* qkv_b  = (const float*)d_in[2];
    const float* proj_w = (const float*)d_in[3];
    const float* proj_b = (const float*)d_in[4];
    const float* rpb    = (const float*)d_in[5];
    float* out = (float*)d_out;

    const int nW = 2 * 5 * 5 * 8 * 8;  // 3200 windows
    const size_t need_w  = (size_t)(49152 + 16384) * sizeof(short);           // 128 KB
    const size_t need_db = need_w + (size_t)16384 * sizeof(float);            // +64 KB

    if (ws_size >= need_db) {
        short* wqs = (short*)d_ws;
        short* wps = wqs + 49152;
        float* bt  = (float*)(wqs + 65536);
        cvt_w_kernel<<<320, 256, 0, stream>>>(qkv_w, proj_w, rpb, wqs, wps, bt);
        win_attn_mfma<true><<<nW, 256, 0, stream>>>(x, wqs, qkv_b, wps, proj_b, bt, out);
    } else if (ws_size >= need_w) {
        short* wqs = (short*)d_ws;
        short* wps = wqs + 49152;
        cvt_w_kernel<<<256, 256, 0, stream>>>(qkv_w, proj_w, rpb, wqs, wps, nullptr);
        win_attn_mfma<false><<<nW, 256, 0, stream>>>(x, wqs, qkv_b, wps, proj_b, rpb, out);
    } else {
        win_attn_fallback<<<nW, 256, 0, stream>>>(x, qkv_w, qkv_b, proj_w, proj_b, rpb, out);
    }
}

// Round 5
// 272.401 us; speedup vs baseline: 1.4353x; 1.0238x over previous
//
#include <hip/hip_runtime.h>

#define NH 4
#define HD 32
#define ST 64          // tokens per window (8x8)
#define CD 128         // DIM
#define IMG 102400     // U*V*H*W
#define VHW 20480      // V*H*W
#define HW_ 4096       // H*W
#define SCALE_ 0.17677669529663687f   // 32^-0.5

typedef __attribute__((ext_vector_type(8))) short bf16x8;
typedef __attribute__((ext_vector_type(4))) float f32x4;
typedef __attribute__((ext_vector_type(4))) int   i32x4;
typedef __attribute__((ext_vector_type(2))) int   i32x2;

__device__ __forceinline__ short f2bf(float f) {
    unsigned int u = __float_as_uint(f);
    u = (u + 0x7FFF + ((u >> 16) & 1)) >> 16;   // RNE
    return (short)u;
}

// packed 2xf32 -> 2xbf16 in one VALU instruction
__device__ __forceinline__ int cvt_pk_bf16(float lo, float hi) {
    int r;
    asm("v_cvt_pk_bf16_f32 %0, %1, %2" : "=v"(r) : "v"(lo), "v"(hi));
    return r;
}

// DPP rotate within each row of 16 lanes: pure-VALU cross-lane (no DS pipe)
template <int N>
__device__ __forceinline__ float row_ror(float v) {
    return __int_as_float(__builtin_amdgcn_update_dpp(
        0, __float_as_int(v), 0x120 | N, 0xF, 0xF, true));
}

// ---- fp32 -> bf16 weight conversion + dense bias table into workspace
// bias layout: bt[h][qi][ln][nt]  (4*64*16*4 floats) so the kernel reads float4
__global__ void cvt_w_kernel(const float* __restrict__ qkv_w,
                             const float* __restrict__ proj_w,
                             const float* __restrict__ rpb,
                             short* __restrict__ wq,
                             short* __restrict__ wp,
                             float* __restrict__ bt) {
    int i = blockIdx.x * 256 + threadIdx.x;   // 81920 threads
    if (i < 49152) wq[i] = f2bf(qkv_w[i]);
    else if (i < 65536) wp[i - 49152] = f2bf(proj_w[i - 49152]);
    else if (i < 81920) {
        int j = i - 65536;                    // bt[h][qi][ln][nt]
        int hh = j >> 12, qi = (j >> 6) & 63, ln2 = (j >> 2) & 15, nt = j & 3;
        int kcol = nt * 16 + ln2;
        int ridx = ((qi >> 3) - (kcol >> 3) + 7) * 15 + ((qi & 7) - (kcol & 7) + 7);
        bt[j] = rpb[ridx * 4 + hh];
    }
}

// LDS map (shorts; total 38400 = 75 KB -> 2 blocks/CU):
//  X      [0, 8704)                 64 x 136  (tok-major, 128 ch + pad 8)
//  head h chunk at 8704 + h*5120:  Q_h [64][40], K_h [64][40]; P_h aliases (64x72)
//  V      [29184, 38400)            per head 32 x 72 (d-major)
//  O   aliases [0, 8704)            64 x 136  (after B2; X dead)
//
// Barriers (3):
//  B1 X-ready; B2 post-GEMM (all X reads done; low-skew point — waves are in
//  lockstep after identical MFMA work); B3 O-ready.  O writes are wave-private
//  columns, P/Q/K/V live outside the O region -> no barrier needed pre-O-write.
//  proj result goes DIRECTLY to global (pa holds 4 consecutive pixels of one
//  channel per f32x4) -> no F staging, no B4.

template <bool DB>   // DB: dense bias table available in ws
__global__ __launch_bounds__(256, 2)
void win_attn_mfma(const float* __restrict__ x,
                   const short* __restrict__ wq,     // bf16 [384][128]
                   const float* __restrict__ qkv_b,
                   const short* __restrict__ wp,     // bf16 [128][128]
                   const float* __restrict__ proj_b,
                   const float* __restrict__ bias,   // DB ? bt[4][64][16][4] : rpb
                   float* __restrict__ out) {
    __shared__ __align__(16) short smem[38400];

    const int t    = threadIdx.x;
    const int h    = __builtin_amdgcn_readfirstlane(t >> 6);  // wave = head
    const int ln   = t & 15;
    const int quad = (t >> 4) & 3;

    // gather mapping: s -> (row gr, 4-px group), cb -> channel block
    const int s     = t & 15;
    const int cb    = t >> 4;          // 0..15, channels cb*8 .. cb*8+7
    const int gr    = s >> 1;          // window row 0..7
    const int ghalf = s & 1;           // px group 0..1 (4 px each)
    const int srow4 = s * 4;           // gr*8 + ghalf*4

    // XCD swizzle: give each XCD 400 contiguous logical windows
    const int wid = (blockIdx.x & 7) * 400 + (blockIdx.x >> 3);
    const int wn = wid & 7, hn = (wid >> 3) & 7;
    int rem = wid >> 6;
    const int v = rem % 5; rem /= 5;
    const int u = rem % 5;
    const int b = rem / 5;
    const long base = (long)b * (CD * IMG) + u * VHW + v * HW_;

    // source pixels: shift by -4 mod 64; 4-px groups stay float4-aligned (4|shift)
    const int hh_r = (((hn << 3) + gr) - 4) & 63;
    const int ww0  = (((wn << 3) + ghalf * 4) - 4) & 63;
    const long pixrs = base + hh_r * 64 + ww0;

    // direct-store coords (thread -> (token fragment, channel) of proj output):
    //  token = mt*16 + quad*4 + r  -> wrow = 2*mt + (quad>>1), wcol0 = (quad&1)*4
    const int ocol = (((wn << 3) + (quad & 1) * 4) - 4) & 63;

    short* X  = smem;                      // [64][136]
    short* Qh = smem + 8704 + h * 5120;    // [64][40]
    short* Kh = Qh + 2560;                 // [64][40]
    short* Ph = Qh;                        // aliases Q_h/K_h (in-wave only), [64][72]
    short* Vh = smem + 29184 + h * 2304;   // [32][72]
    short* O  = smem;                      // [64][136] (aliases X)

    // ---- float4 gather: 8 vector loads/thread, all in flight ----
    float4 xv[8];
    #pragma unroll
    for (int j = 0; j < 8; ++j)
        xv[j] = *(const float4*)(x + pixrs + (long)(cb * 8 + j) * IMG);

    // ---- prefetch ALL QKV B-fragments (independent of X) ----
    bf16x8 wqf[24];
    #pragma unroll
    for (int kh = 0; kh < 4; ++kh)
        #pragma unroll
        for (int n = 0; n < 6; ++n)
            wqf[kh * 6 + n] = *(const bf16x8*)(wq + (h * 96 + n * 16 + ln) * 128 + kh * 32 + quad * 8);
    float qb[6];
    #pragma unroll
    for (int n = 0; n < 6; ++n) qb[n] = qkv_b[h * 96 + n * 16 + ln];

    // ---- X pack: cvt_pk + b128 stores ----
    #pragma unroll
    for (int px = 0; px < 4; ++px) {
        i32x4 pk;
        #pragma unroll
        for (int j2 = 0; j2 < 4; ++j2)
            pk[j2] = cvt_pk_bf16(((const float*)&xv[2 * j2])[px],
                                 ((const float*)&xv[2 * j2 + 1])[px]);
        *(i32x4*)(X + (srow4 + px) * 136 + cb * 8) = pk;
    }
    __syncthreads();                       // B1: X ready

    // ================= QKV GEMM: (64x128) @ (128x384)^T =================
    f32x4 acc[6][4];
    #pragma unroll
    for (int n = 0; n < 6; ++n)
        #pragma unroll
        for (int mt = 0; mt < 4; ++mt) acc[n][mt] = (f32x4){0.f, 0.f, 0.f, 0.f};

    #pragma unroll
    for (int kh = 0; kh < 4; ++kh) {
        bf16x8 af[4];
        #pragma unroll
        for (int mt = 0; mt < 4; ++mt)
            af[mt] = *(const bf16x8*)(X + (mt * 16 + ln) * 136 + kh * 32 + quad * 8);
        __builtin_amdgcn_s_setprio(1);
        #pragma unroll
        for (int n = 0; n < 6; ++n)
            #pragma unroll
            for (int mt = 0; mt < 4; ++mt)
                acc[n][mt] = __builtin_amdgcn_mfma_f32_16x16x32_bf16(af[mt], wqf[kh * 6 + n], acc[n][mt], 0, 0, 0);
        __builtin_amdgcn_s_setprio(0);
    }
    __syncthreads();   // B2: all X reads done (low-skew: waves lockstep post-GEMM)

    // ---- D-tiles -> LDS: Q (scaled) / K token-major (scalar) ----
    #pragma unroll
    for (int n = 0; n < 4; ++n) {
        const float bv_ = qb[n];
        short* dst = (n < 2) ? Qh : Kh;
        const int col = (n & 1) * 16 + ln;
        #pragma unroll
        for (int mt = 0; mt < 4; ++mt)
            #pragma unroll
            for (int r = 0; r < 4; ++r) {
                const float val = acc[n][mt][r] + bv_;
                const int tk = mt * 16 + quad * 4 + r;
                dst[tk * 40 + col] = f2bf((n < 2) ? val * SCALE_ : val);
            }
    }
    // ---- V d-major: 4 consecutive tokens -> packed b64 stores ----
    #pragma unroll
    for (int n = 4; n < 6; ++n) {
        const float bv_ = qb[n];
        const int d = (n - 4) * 16 + ln;
        #pragma unroll
        for (int mt = 0; mt < 4; ++mt) {
            const int tk0 = mt * 16 + quad * 4;
            i32x2 pv;
            pv[0] = cvt_pk_bf16(acc[n][mt][0] + bv_, acc[n][mt][1] + bv_);
            pv[1] = cvt_pk_bf16(acc[n][mt][2] + bv_, acc[n][mt][3] + bv_);
            *(i32x2*)(Vh + d * 72 + tk0) = pv;
        }
    }
    // Q/K/V/P strictly per-head, per-wave: no barrier until B3.

    // ================= S = Q K^T (64x64, K=32) =================
    bf16x8 aq[4], bk[4];
    #pragma unroll
    for (int mt = 0; mt < 4; ++mt) aq[mt] = *(const bf16x8*)(Qh + (mt * 16 + ln) * 40 + quad * 8);
    #pragma unroll
    for (int nt = 0; nt < 4; ++nt) bk[nt] = *(const bf16x8*)(Kh + (nt * 16 + ln) * 40 + quad * 8);

    // prefetch dense bias early (independent of S): 16 float4, L2-hot
    f32x4 bb[4][4];
    if (DB) {
        const float* bt = bias + h * 4096;     // [qi][ln][nt]
        #pragma unroll
        for (int mt = 0; mt < 4; ++mt)
            #pragma unroll
            for (int r = 0; r < 4; ++r) {
                const int qi = mt * 16 + quad * 4 + r;
                bb[mt][r] = *(const f32x4*)(bt + (qi * 16 + ln) * 4);
            }
    }

    f32x4 sm[4][4];
    __builtin_amdgcn_s_setprio(1);
    #pragma unroll
    for (int mt = 0; mt < 4; ++mt)
        #pragma unroll
        for (int nt = 0; nt < 4; ++nt) {
            f32x4 z = (f32x4){0.f, 0.f, 0.f, 0.f};
            sm[mt][nt] = __builtin_amdgcn_mfma_f32_16x16x32_bf16(aq[mt], bk[nt], z, 0, 0, 0);
        }
    __builtin_amdgcn_s_setprio(0);

    // relative-position bias
    if (DB) {
        #pragma unroll
        for (int mt = 0; mt < 4; ++mt)
            #pragma unroll
            for (int r = 0; r < 4; ++r)
                #pragma unroll
                for (int nt = 0; nt < 4; ++nt)
                    sm[mt][nt][r] += bb[mt][r][nt];
    } else {
        #pragma unroll
        for (int nt = 0; nt < 4; ++nt) {
            const int kcol = nt * 16 + ln;
            const int ik = kcol >> 3, jk = kcol & 7;
            #pragma unroll
            for (int mt = 0; mt < 4; ++mt)
                #pragma unroll
                for (int r = 0; r < 4; ++r) {
                    const int q = mt * 16 + quad * 4 + r;
                    const int ridx = ((q >> 3) - ik + 7) * 15 + ((q & 7) - jk + 7);
                    sm[mt][nt][r] += bias[ridx * 4 + h];
                }
        }
    }

    // softmax rows: row=(mt,r); cols span nt x 16 lanes of the quad (DPP reduce)
    float inv[4][4];
    #pragma unroll
    for (int mt = 0; mt < 4; ++mt)
        #pragma unroll
        for (int r = 0; r < 4; ++r) {
            float m = fmaxf(fmaxf(sm[mt][0][r], sm[mt][1][r]), fmaxf(sm[mt][2][r], sm[mt][3][r]));
            m = fmaxf(m, row_ror<1>(m));
            m = fmaxf(m, row_ror<2>(m));
            m = fmaxf(m, row_ror<4>(m));
            m = fmaxf(m, row_ror<8>(m));
            float sum = 0.f;
            #pragma unroll
            for (int nt = 0; nt < 4; ++nt) {
                float e = __expf(sm[mt][nt][r] - m);
                sm[mt][nt][r] = e;
                sum += e;
            }
            const int q = mt * 16 + quad * 4 + r;
            #pragma unroll
            for (int nt = 0; nt < 4; ++nt)
                Ph[q * 72 + nt * 16 + ln] = f2bf(sm[mt][nt][r]);   // unnormalized P
            sum += row_ror<1>(sum);
            sum += row_ror<2>(sum);
            sum += row_ror<4>(sum);
            sum += row_ror<8>(sum);
            inv[mt][r] = 1.f / sum;
        }

    // prefetch proj B-fragments during softmax slack
    bf16x8 wpf[8];
    #pragma unroll
    for (int kt = 0; kt < 4; ++kt)
        #pragma unroll
        for (int nt = 0; nt < 2; ++nt)
            wpf[kt * 2 + nt] = *(const bf16x8*)(wp + (h * 32 + nt * 16 + ln) * 128 + kt * 32 + quad * 8);
    float pb[2];
    #pragma unroll
    for (int nt = 0; nt < 2; ++nt) pb[nt] = proj_b[h * 32 + nt * 16 + ln];

    // ================= O = P V (64x32, K=64) =================
    f32x4 oa[4][2];
    #pragma unroll
    for (int mt = 0; mt < 4; ++mt)
        #pragma unroll
        for (int nt = 0; nt < 2; ++nt) oa[mt][nt] = (f32x4){0.f, 0.f, 0.f, 0.f};
    #pragma unroll
    for (int kt = 0; kt < 2; ++kt) {
        bf16x8 ap[4], bv[2];
        #pragma unroll
        for (int mt = 0; mt < 4; ++mt)
            ap[mt] = *(const bf16x8*)(Ph + (mt * 16 + ln) * 72 + kt * 32 + quad * 8);
        #pragma unroll
        for (int nt = 0; nt < 2; ++nt)
            bv[nt] = *(const bf16x8*)(Vh + (nt * 16 + ln) * 72 + kt * 32 + quad * 8);
        __builtin_amdgcn_s_setprio(1);
        #pragma unroll
        for (int mt = 0; mt < 4; ++mt)
            #pragma unroll
            for (int nt = 0; nt < 2; ++nt)
                oa[mt][nt] = __builtin_amdgcn_mfma_f32_16x16x32_bf16(ap[mt], bv[nt], oa[mt][nt], 0, 0, 0);
        __builtin_amdgcn_s_setprio(0);
    }

    // O write: columns h*32..h*32+31 are wave-private; X is dead since B2.
    #pragma unroll
    for (int mt = 0; mt < 4; ++mt)
        #pragma unroll
        for (int nt = 0; nt < 2; ++nt)
            #pragma unroll
            for (int r = 0; r < 4; ++r)
                O[(mt * 16 + quad * 4 + r) * 136 + h * 32 + nt * 16 + ln] =
                    f2bf(oa[mt][nt][r] * inv[mt][r]);
    __syncthreads();              // B3: O ready

    // ================= proj: (64x128) @ (128x128)^T =================
    f32x4 pa[4][2];
    #pragma unroll
    for (int mt = 0; mt < 4; ++mt)
        #pragma unroll
        for (int nt = 0; nt < 2; ++nt) pa[mt][nt] = (f32x4){0.f, 0.f, 0.f, 0.f};
    #pragma unroll
    for (int kt = 0; kt < 4; ++kt) {
        bf16x8 ao[4];
        #pragma unroll
        for (int mt = 0; mt < 4; ++mt)
            ao[mt] = *(const bf16x8*)(O + (mt * 16 + ln) * 136 + kt * 32 + quad * 8);
        __builtin_amdgcn_s_setprio(1);
        #pragma unroll
        for (int mt = 0; mt < 4; ++mt)
            #pragma unroll
            for (int nt = 0; nt < 2; ++nt)
                pa[mt][nt] = __builtin_amdgcn_mfma_f32_16x16x32_bf16(ao[mt], wpf[kt * 2 + nt], pa[mt][nt], 0, 0, 0);
        __builtin_amdgcn_s_setprio(0);
    }

    // ---- direct global store: pa[mt][nt] = 4 consecutive pixels (float4) of
    //      channel c = h*32+nt*16+ln, window row 2*mt+(quad>>1). No F staging.
    #pragma unroll
    for (int mt = 0; mt < 4; ++mt) {
        const int orow = (((hn << 3) + 2 * mt + (quad >> 1)) - 4) & 63;
        const long prow = base + orow * 64 + ocol;
        #pragma unroll
        for (int nt = 0; nt < 2; ++nt) {
            const int c = h * 32 + nt * 16 + ln;
            f32x4 fv = pa[mt][nt] + pb[nt];
            *(f32x4*)(out + prow + (long)c * IMG) = fv;
        }
    }
}

// ---------- fp32 fallback (only if workspace is too small even for weights) ----------
__global__ __launch_bounds__(256, 1)
void win_attn_fallback(const float* __restrict__ x,
                       const float* __restrict__ wQKV,
                       const float* __restrict__ qkv_b,
                       const float* __restrict__ wP,
                       const float* __restrict__ proj_b,
                       const float* __restrict__ rpb,
                       float* __restrict__ out) {
    __shared__ __align__(16) float k_lds[NH * ST * HD];
    __shared__ __align__(16) float v_lds[NH * ST * HD];
    const int t = threadIdx.x;
    const int h = __builtin_amdgcn_readfirstlane(t >> 6);
    const int l = t & 63;
    const int wid = blockIdx.x;
    const int wn = wid & 7, hn = (wid >> 3) & 7;
    int rem = wid >> 6;
    const int v = rem % 5; rem /= 5;
    const int u = rem % 5;
    const int b = rem / 5;
    const int hh = (((hn << 3) + (l >> 3)) - 4) & 63;
    const int ww = (((wn << 3) + (l & 7)) - 4) & 63;
    const int pix = b * (NH * HD * IMG) + u * VHW + v * HW_ + hh * 64 + ww;
    float q[HD], kk[HD], vv[HD];
    const float* bq = qkv_b + h * 96;
    #pragma unroll
    for (int d = 0; d < HD; ++d) { q[d] = bq[d]; kk[d] = bq[32 + d]; vv[d] = bq[64 + d]; }
    for (int c = 0; c < CD; ++c) {
        float xv = x[pix + c * IMG];
        const float* wc = wQKV + h * 96 * CD + c;
        #pragma unroll
        for (int d = 0; d < HD; ++d) {
            q[d]  = fmaf(xv, wc[d * CD], q[d]);
            kk[d] = fmaf(xv, wc[(32 + d) * CD], kk[d]);
            vv[d] = fmaf(xv, wc[(64 + d) * CD], vv[d]);
        }
    }
    float* kr = k_lds + (h * ST + l) * HD;
    float* vr = v_lds + (h * ST + l) * HD;
    #pragma unroll
    for (int d = 0; d < HD; ++d) { kr[d] = kk[d]; vr[d] = vv[d]; }
    __syncthreads();
    const float* kh2 = k_lds + h * ST * HD;
    const float* vh2 = v_lds + h * ST * HD;
    const int iq = l >> 3, jq = l & 7;
    float m = -1e30f;
    for (int sk = 0; sk < ST; ++sk) {
        const float* kp = kh2 + sk * HD;
        float a2 = 0.f;
        #pragma unroll
        for (int d = 0; d < HD; ++d) a2 = fmaf(q[d], kp[d], a2);
        int ridx = (iq - (sk >> 3) + 7) * 15 + (jq - (sk & 7) + 7);
        m = fmaxf(m, fmaf(a2, SCALE_, rpb[ridx * 4 + h]));
    }
    float o[HD];
    #pragma unroll
    for (int d = 0; d < HD; ++d) o[d] = 0.f;
    float ssum = 0.f;
    for (int sk = 0; sk < ST; ++sk) {
        const float* kp = kh2 + sk * HD;
        float a2 = 0.f;
        #pragma unroll
        for (int d = 0; d < HD; ++d) a2 = fmaf(q[d], kp[d], a2);
        int ridx = (iq - (sk >> 3) + 7) * 15 + (jq - (sk & 7) + 7);
        float e = __expf(fmaf(a2, SCALE_, rpb[ridx * 4 + h]) - m);
        ssum += e;
        const float* vp = vh2 + sk * HD;
        #pragma unroll
        for (int d = 0; d < HD; ++d) o[d] = fmaf(e, vp[d], o[d]);
    }
    const float inv = 1.f / ssum;
    __syncthreads();
    float* ot = k_lds;
    #pragma unroll
    for (int d = 0; d < HD; ++d) ot[(h * HD + d) * ST + l] = o[d] * inv;
    __syncthreads();
    float o2[HD];
    const float* pb2 = proj_b + h * HD;
    #pragma unroll
    for (int j = 0; j < HD; ++j) o2[j] = pb2[j];
    for (int c = 0; c < CD; ++c) {
        float xv = ot[c * ST + l];
        const float* pc = wP + h * HD * CD + c;
        #pragma unroll
        for (int j = 0; j < HD; ++j) o2[j] = fmaf(xv, pc[j * CD], o2[j]);
    }
    float* ob = out + pix;
    #pragma unroll
    for (int j = 0; j < HD; ++j) ob[(h * HD + j) * IMG] = o2[j];
}

extern "C" void kernel_launch(void* const* d_in, const int* in_sizes, int n_in,
                              void* d_out, int out_size, void* d_ws, size_t ws_size,
                              hipStream_t stream) {
    const float* x      = (const float*)d_in[0];
    const float* qkv_w  = (const float*)d_in[1];
    const float* qkv_b  = (const float*)d_in[2];
    const float* proj_w = (const float*)d_in[3];
    const float* proj_b = (const float*)d_in[4];
    const float* rpb    = (const float*)d_in[5];
    float* out = (float*)d_out;

    const int nW = 2 * 5 * 5 * 8 * 8;  // 3200 windows
    const size_t need_w  = (size_t)(49152 + 16384) * sizeof(short);           // 128 KB
    const size_t need_db = need_w + (size_t)16384 * sizeof(float);            // +64 KB

    if (ws_size >= need_db) {
        short* wqs = (short*)d_ws;
        short* wps = wqs + 49152;
        float* bt  = (float*)(wqs + 65536);
        cvt_w_kernel<<<320, 256, 0, stream>>>(qkv_w, proj_w, rpb, wqs, wps, bt);
        win_attn_mfma<true><<<nW, 256, 0, stream>>>(x, wqs, qkv_b, wps, proj_b, bt, out);
    } else if (ws_size >= need_w) {
        short* wqs = (short*)d_ws;
        short* wps = wqs + 49152;
        cvt_w_kernel<<<256, 256, 0, stream>>>(qkv_w, proj_w, rpb, wqs, wps, nullptr);
        win_attn_mfma<false><<<nW, 256, 0, stream>>>(x, wqs, qkv_b, wps, proj_b, rpb, out);
    } else {
        win_attn_fallback<<<nW, 256, 0, stream>>>(x, qkv_w, qkv_b, proj_w, proj_b, rpb, out);
    }
}